// Round 6
// baseline (3414.304 us; speedup 1.0000x reference)
//
#include <hip/hip_runtime.h>

typedef __bf16 bf16_t;
typedef bf16_t bf16x8 __attribute__((ext_vector_type(8)));
typedef float  f32x4  __attribute__((ext_vector_type(4)));

#define TT 512
#define BB 1024

// packed weight chunk bases (16B chunks). Layer k: [N,K] row-major source.
#define cL0   0      // enc1_s  N=128 K=64   (folded We1a*Wphi_s)
#define cL1   1024   // enc1_h  N=128 K=128  (We1[:,128:])
#define cL2   3072   // enc2    N=128 K=128
#define cL3   5120   // pri1    N=128 K=128
#define cL4   7168   // pri2    N=128 K=128
#define cL5   9216   // dec1_z  N=128 K=64   (folded Wd1a*Wphi_z)
#define cL6   10240  // dec1_h  N=128 K=128  (Wd1[:,128:])
#define cL7   12288  // dec2    N=64  K=128
#define cL8   13312  // gates_s N=512 K=64   (folded Wih_a*Wphi_s)
#define cL9   17408  // gates_z N=512 K=64   (folded Wih_b*Wphi_z)
#define cL10  21504  // gates_h N=512 K=128  (W_hh)
#define NCHUNK 29696

#define WS_FBIAS_OFF 475136            // 768 floats (b_enc1f[128], b_dec1f[128], b_g[512])
#define WS_FOLD_OFF  478208            // 81920 floats

__device__ __forceinline__ f32x4 mfma16(bf16x8 a, bf16x8 b, f32x4 c) {
  return __builtin_amdgcn_mfma_f32_16x16x32_bf16(a, b, c, 0, 0, 0);
}
__device__ __forceinline__ float sigm(float x) { return 1.0f / (1.0f + __expf(-x)); }
__device__ __forceinline__ float tanh_f(float x) {
  x = fminf(fmaxf(x, -15.0f), 15.0f);
  float e = __expf(2.0f * x);
  return (e - 1.0f) / (e + 1.0f);
}
__device__ __forceinline__ float softplus_f(float x) {
  return (x > 15.0f) ? x : __logf(1.0f + __expf(x));
}
// LDS-only barrier: no vmcnt drain (global loads wait at their use).
__device__ __forceinline__ void wg_barrier() {
  asm volatile("s_waitcnt lgkmcnt(0)\n\ts_barrier" ::: "memory");
}
// Wave-local LDS fence: z scratch written+read by the SAME wave, no s_barrier.
__device__ __forceinline__ void wave_lds_fence() {
  asm volatile("s_waitcnt lgkmcnt(0)" ::: "memory");
  __builtin_amdgcn_sched_barrier(0);
}
// Pin a loaded fragment as an opaque asm result (forced register residency).
__device__ __forceinline__ void keep(bf16x8& v) { asm volatile("" : "+v"(v)); }

// ---------------- setup kernel 1: fold phi layers into downstream weights ----------------
__global__ void vrnn_fold(const float* __restrict__ We1, const float* __restrict__ Wd1,
                          const float* __restrict__ Wih,
                          const float* __restrict__ Wps, const float* __restrict__ Wpz,
                          const float* __restrict__ bps, const float* __restrict__ bpz,
                          const float* __restrict__ be1, const float* __restrict__ bd1,
                          const float* __restrict__ bih, const float* __restrict__ bhh,
                          float* __restrict__ fold, float* __restrict__ fbias) {
  int id = blockIdx.x * 256 + threadIdx.x;
  if (id < 8192) {                                  // A_es = We1[:, :128] @ Wphi_s  [128,64]
    int n = id >> 6, k = id & 63; float acc = 0.f;
    for (int j = 0; j < 128; ++j) acc += We1[n*256 + j] * Wps[j*64 + k];
    fold[id] = acc;
  } else if (id < 16384) {                          // A_ds = Wd1[:, :128] @ Wphi_z  [128,64]
    int q = id - 8192; int n = q >> 6, k = q & 63; float acc = 0.f;
    for (int j = 0; j < 128; ++j) acc += Wd1[n*256 + j] * Wpz[j*64 + k];
    fold[id] = acc;
  } else if (id < 49152) {                          // G_s = Wih[:, :128] @ Wphi_s  [512,64]
    int q = id - 16384; int n = q >> 6, k = q & 63; float acc = 0.f;
    for (int j = 0; j < 128; ++j) acc += Wih[n*256 + j] * Wps[j*64 + k];
    fold[id] = acc;
  } else if (id < 81920) {                          // G_z = Wih[:, 128:] @ Wphi_z  [512,64]
    int q = id - 49152; int n = q >> 6, k = q & 63; float acc = 0.f;
    for (int j = 0; j < 128; ++j) acc += Wih[n*256 + 128 + j] * Wpz[j*64 + k];
    fold[id] = acc;
  } else if (id < 82048) {                          // b_enc1f = be1 + We1a@b_phi_s
    int n = id - 81920; float acc = be1[n];
    for (int j = 0; j < 128; ++j) acc += We1[n*256 + j] * bps[j];
    fbias[n] = acc;
  } else if (id < 82176) {                          // b_dec1f = bd1 + Wd1a@b_phi_z
    int n = id - 82048; float acc = bd1[n];
    for (int j = 0; j < 128; ++j) acc += Wd1[n*256 + j] * bpz[j];
    fbias[128 + n] = acc;
  } else if (id < 82688) {                          // b_g = bih + bhh + Wih_a@bps + Wih_b@bpz
    int n = id - 82176; float acc = bih[n] + bhh[n];
    for (int j = 0; j < 128; ++j) acc += Wih[n*256 + j]*bps[j] + Wih[n*256 + 128 + j]*bpz[j];
    fbias[256 + n] = acc;
  }
}

// ---------------- setup kernel 2: pack all layers into MFMA B-fragment order -------------
__global__ void vrnn_pack(const float* __restrict__ fold,
                          const float* __restrict__ We1, const float* __restrict__ We2,
                          const float* __restrict__ Wp1, const float* __restrict__ Wp2,
                          const float* __restrict__ Wd1, const float* __restrict__ Wd2,
                          const float* __restrict__ Whh,
                          bf16_t* __restrict__ packed) {
  int c = blockIdx.x * 256 + threadIdx.x;
  if (c >= NCHUNK) return;
  const float* src; int rs, co, Kt, base;
  if      (c < 1024)  { base = cL0;  src = fold;          rs = 64;  co = 0;   Kt = 2; }
  else if (c < 3072)  { base = cL1;  src = We1;           rs = 256; co = 128; Kt = 4; }
  else if (c < 5120)  { base = cL2;  src = We2;           rs = 128; co = 0;   Kt = 4; }
  else if (c < 7168)  { base = cL3;  src = Wp1;           rs = 128; co = 0;   Kt = 4; }
  else if (c < 9216)  { base = cL4;  src = Wp2;           rs = 128; co = 0;   Kt = 4; }
  else if (c < 10240) { base = cL5;  src = fold + 8192;   rs = 64;  co = 0;   Kt = 2; }
  else if (c < 12288) { base = cL6;  src = Wd1;           rs = 256; co = 128; Kt = 4; }
  else if (c < 13312) { base = cL7;  src = Wd2;           rs = 128; co = 0;   Kt = 4; }
  else if (c < 17408) { base = cL8;  src = fold + 16384;  rs = 64;  co = 0;   Kt = 2; }
  else if (c < 21504) { base = cL9;  src = fold + 49152;  rs = 64;  co = 0;   Kt = 2; }
  else                { base = cL10; src = Whh;           rs = 128; co = 0;   Kt = 4; }
  int local = c - base;
  int nt = local / (Kt * 64);
  int r = local - nt * Kt * 64;
  int kt = r >> 6, lane = r & 63;
  int n = nt * 16 + (lane & 15);
  int k = kt * 32 + (lane >> 4) * 8;
  const float* p = src + n * rs + co + k;
  bf16x8 v;
  #pragma unroll
  for (int j = 0; j < 8; ++j) v[j] = (bf16_t)p[j];
  *(bf16x8*)(packed + (size_t)c * 8) = v;
}

// ---------------- fused 2-barrier kernel ----------------
// P1: dec2+recon(t-1, w4-7) | gates-s/h | enc1 | pri1.            B1.
// P2: enc2 REPLICATED per wave -> z in-registers -> wave-private LDS convert
//     (lgkmcnt only, no barrier) -> gates-z + LSTM + dec1 + KL.   B2.
// Pinned 128 regs (rb10/rb8/rb9); enc2/pri2/pri1/dec2 in 112KB LDS; wE/wD1/w5 L2-streamed.
__global__ __launch_bounds__(512, 2) void vrnn_fuse2(
    const float* __restrict__ s, const float* __restrict__ noise,
    const bf16_t* __restrict__ packed, const float* __restrict__ fbias,
    const float* __restrict__ bp1, const float* __restrict__ bp2,
    const float* __restrict__ be2, const float* __restrict__ bd2,
    float* __restrict__ out) {
  const bf16x8* Wf = (const bf16x8*)packed;

  __shared__ __align__(16) bf16_t A_h[2][16 * 136];
  __shared__ __align__(16) bf16_t A_s[16 * 72];
  __shared__ __align__(16) bf16_t A_e1[16 * 136];
  __shared__ __align__(16) bf16_t A_p1[16 * 136];
  __shared__ __align__(16) bf16_t A_d1[16 * 136];
  __shared__ __align__(16) bf16_t zscr[8][16 * 72];   // wave-private z scratch
  __shared__ __align__(16) bf16_t Wlds[7168 * 8];     // 112KB: enc2@0 pri2@2048 pri1@4096 dec2@6144
  __shared__ float bsm[1216]; // [0)be1f [128)bp1 [256)be2 [384)bp2 [512)bd1f [640)bd2 [704)b_g
  __shared__ float red[8];

  const int tid  = threadIdx.x;
  const int wv   = tid >> 6, ln = tid & 63;
  const int quad = ln >> 4, col = ln & 15;
  const int row0 = blockIdx.x * 16;
  const int pm_  = tid >> 5;
  const int pj   = (tid & 31) * 2;
  const int nloc0 = wv * 16 + col;
  const int j_own = wv * 16 + col;
  const int wq   = wv & 3;

  for (int i = tid; i < 1216; i += 512) {
    float v;
    if      (i < 128)  v = fbias[i];
    else if (i < 256)  v = bp1[i - 128];
    else if (i < 384)  v = be2[i - 256];
    else if (i < 512)  v = bp2[i - 384];
    else if (i < 640)  v = fbias[128 + (i - 512)];
    else if (i < 704)  v = bd2[i - 640];
    else               v = fbias[256 + (i - 704)];
    bsm[i] = v;
  }
  { // stage enc2/pri2/pri1/dec2 weights into LDS once (7168 chunks = 112KB)
    bf16x8* wl = (bf16x8*)Wlds;
    for (int c = tid; c < 7168; c += 512) {
      int g;
      if      (c < 2048) g = cL2 + c;
      else if (c < 4096) g = cL4 + (c - 2048);
      else if (c < 6144) g = cL3 + (c - 4096);
      else               g = cL7 + (c - 6144);
      wl[c] = Wf[g];
    }
  }
  for (int i = tid; i < 16 * 136; i += 512) A_h[0][i] = (bf16_t)0.0f;

  // ---- pinned resident weights: 32 frags = 128 regs ----
  bf16x8 rb10[4][4], rb8[4][2], rb9[4][2];
  #pragma unroll
  for (int i = 0; i < 4; ++i) {
    int nt = wv + 8 * i;
    #pragma unroll
    for (int k = 0; k < 4; ++k) { rb10[i][k] = Wf[cL10 + (nt * 4 + k) * 64 + ln]; keep(rb10[i][k]); }
    rb8[i][0] = Wf[cL8 + (nt * 2 + 0) * 64 + ln]; keep(rb8[i][0]);
    rb8[i][1] = Wf[cL8 + (nt * 2 + 1) * 64 + ln]; keep(rb8[i][1]);
    rb9[i][0] = Wf[cL9 + (nt * 2 + 0) * 64 + ln]; keep(rb9[i][0]);
    rb9[i][1] = Wf[cL9 + (nt * 2 + 1) * 64 + ln]; keep(rb9[i][1]);
  }

  // ---- rolling per-thread state ----
  float nz16[16];   // noise[t] in enc2 C-layout: [nt*4+r] -> noise[row0+quad*4+r][nt*16+col]
  #pragma unroll
  for (int nt = 0; nt < 4; ++nt)
    #pragma unroll
    for (int r = 0; r < 4; ++r)
      nz16[nt * 4 + r] = noise[((size_t)0 * BB + row0 + quad * 4 + r) * 64 + nt * 16 + col];
  float pre4[4] = {0.f, 0.f, 0.f, 0.f};   // w4-7: s[t] C-layout for recon
  float2 svN = *(const float2*)(s + ((size_t)1 * BB + row0 + pm_) * 64 + pj);
  { // stage s_0
    float2 v = *(const float2*)(s + ((size_t)0 * BB + row0 + pm_) * 64 + pj);
    A_s[pm_ * 72 + pj]     = (bf16_t)v.x;
    A_s[pm_ * 72 + pj + 1] = (bf16_t)v.y;
  }

  f32x4 c_reg = {0.f, 0.f, 0.f, 0.f};
  float kl_acc = 0.0f, rc_acc = 0.0f;
  __syncthreads();

  int cb = 0;
  for (int t = 0; t < TT; ++t) {
    // ================= P1 =================
    int lz1 = 0;
    asm volatile("" : "+s"(lz1));
    const bf16x8* WL1 = (const bf16x8*)Wlds + lz1;
    const bf16x8* WG1 = Wf + lz1;
    // stream enc1 weights (consumed mid-P1; L2 latency hidden under gates/dec2)
    bf16x8 wEs[6];
    wEs[0] = WG1[cL0 + (wv * 2 + 0) * 64 + ln];
    wEs[1] = WG1[cL0 + (wv * 2 + 1) * 64 + ln];
    #pragma unroll
    for (int k = 0; k < 4; ++k) wEs[2 + k] = WG1[cL1 + (wv * 4 + k) * 64 + ln];

    if (wv >= 4 && t > 0) {  // dec2(t-1) -> recon (LDS weights, rolling)
      float bv = bsm[640 + wq * 16 + col];
      f32x4 c = {bv, bv, bv, bv};
      #pragma unroll
      for (int k = 0; k < 4; ++k) {
        bf16x8 ad = *(const bf16x8*)&A_d1[col * 136 + k * 32 + quad * 8];
        c = mfma16(ad, WL1[6144 + (wq * 4 + k) * 64 + ln], c);
      }
      #pragma unroll
      for (int r = 0; r < 4; ++r) {
        float d = c[r] - pre4[r];
        rc_acc += 0.5f * d * d;
      }
    }
    bf16x8 ah0 = *(const bf16x8*)&A_h[cb][col * 136 + 0 + quad * 8];
    bf16x8 ah1 = *(const bf16x8*)&A_h[cb][col * 136 + 32 + quad * 8];
    bf16x8 ah2 = *(const bf16x8*)&A_h[cb][col * 136 + 64 + quad * 8];
    bf16x8 ah3 = *(const bf16x8*)&A_h[cb][col * 136 + 96 + quad * 8];
    bf16x8 as0 = *(const bf16x8*)&A_s[col * 72 + 0 + quad * 8];
    bf16x8 as1 = *(const bf16x8*)&A_s[col * 72 + 32 + quad * 8];

    f32x4 Cg[4];  // gates s+h partial; finished in P2 with z
    #pragma unroll
    for (int i = 0; i < 4; ++i) {
      float bv = bsm[704 + j_own + 128 * i];
      f32x4 cc = {bv, bv, bv, bv};
      cc = mfma16(ah0, rb10[i][0], cc);
      cc = mfma16(ah1, rb10[i][1], cc);
      cc = mfma16(ah2, rb10[i][2], cc);
      cc = mfma16(ah3, rb10[i][3], cc);
      cc = mfma16(as0, rb8[i][0], cc);
      cc = mfma16(as1, rb8[i][1], cc);
      Cg[i] = cc;
    }
    {  // enc1 (streamed weights) -> A_e1
      float bv = bsm[nloc0];
      f32x4 c = {bv, bv, bv, bv};
      c = mfma16(as0, wEs[0], c);
      c = mfma16(as1, wEs[1], c);
      c = mfma16(ah0, wEs[2], c);
      c = mfma16(ah1, wEs[3], c);
      c = mfma16(ah2, wEs[4], c);
      c = mfma16(ah3, wEs[5], c);
      #pragma unroll
      for (int r = 0; r < 4; ++r)
        A_e1[(quad * 4 + r) * 136 + nloc0] = (bf16_t)fmaxf(c[r], 0.0f);
    }
    {  // pri1 (LDS weights, rolling) -> A_p1
      float bv = bsm[128 + nloc0];
      f32x4 c = {bv, bv, bv, bv};
      c = mfma16(ah0, WL1[4096 + (wv * 4 + 0) * 64 + ln], c);
      c = mfma16(ah1, WL1[4096 + (wv * 4 + 1) * 64 + ln], c);
      c = mfma16(ah2, WL1[4096 + (wv * 4 + 2) * 64 + ln], c);
      c = mfma16(ah3, WL1[4096 + (wv * 4 + 3) * 64 + ln], c);
      #pragma unroll
      for (int r = 0; r < 4; ++r)
        A_p1[(quad * 4 + r) * 136 + nloc0] = (bf16_t)fmaxf(c[r], 0.0f);
    }
    wg_barrier();  // B1

    // ================= P2 =================
    int lz2 = 0;
    asm volatile("" : "+s"(lz2));
    const bf16x8* WL2 = (const bf16x8*)Wlds + lz2;
    const bf16x8* WG2 = Wf + lz2;

    // stage s_{t+1}; refill svN; w4-7 load s[t] (C-layout) for next-step recon
    if (t + 1 < TT) {
      A_s[pm_ * 72 + pj]     = (bf16_t)svN.x;
      A_s[pm_ * 72 + pj + 1] = (bf16_t)svN.y;
    }
    if (t + 2 < TT)
      svN = *(const float2*)(s + ((size_t)(t + 2) * BB + row0 + pm_) * 64 + pj);
    if (wv >= 4) {
      #pragma unroll
      for (int r = 0; r < 4; ++r)
        pre4[r] = s[((size_t)t * BB + row0 + quad * 4 + r) * 64 + wq * 16 + col];
    }

    // ---- enc2 replicated: every wave computes full z (4 N-tiles) ----
    bf16x8 ae[4];
    #pragma unroll
    for (int k = 0; k < 4; ++k)
      ae[k] = *(const bf16x8*)&A_e1[col * 136 + k * 32 + quad * 8];
    float zmK[4] = {0.f, 0.f, 0.f, 0.f}, zsK[4] = {0.f, 0.f, 0.f, 0.f};
    #pragma unroll
    for (int nt = 0; nt < 4; ++nt) {
      float bm = bsm[256 + nt * 16 + col], bs = bsm[256 + 64 + nt * 16 + col];
      f32x4 cm = {bm, bm, bm, bm};
      f32x4 cs = {bs, bs, bs, bs};
      #pragma unroll
      for (int k = 0; k < 4; ++k) {
        bf16x8 wmu = WL2[(nt * 4 + k) * 64 + ln];
        bf16x8 wsd = WL2[((nt + 4) * 4 + k) * 64 + ln];
        cm = mfma16(ae[k], wmu, cm);
        cs = mfma16(ae[k], wsd, cs);
      }
      #pragma unroll
      for (int r = 0; r < 4; ++r) {
        float zs = softplus_f(cs[r]);
        float z  = cm[r] + zs * nz16[nt * 4 + r];
        zscr[wv][(quad * 4 + r) * 72 + nt * 16 + col] = (bf16_t)z;
        if (wv < 4 && nt == wq) { zmK[r] = cm[r]; zsK[r] = zs; }
      }
    }
    // ---- pri2 + KL on waves 0-3 (own N-tile only; exactly-once coverage) ----
    if (wv < 4) {
      f32x4 cm, cs;
      {
        float bm = bsm[384 + wq * 16 + col], bs = bsm[384 + 64 + wq * 16 + col];
        cm = (f32x4){bm, bm, bm, bm};
        cs = (f32x4){bs, bs, bs, bs};
      }
      #pragma unroll
      for (int k = 0; k < 4; ++k) {
        bf16x8 ap = *(const bf16x8*)&A_p1[col * 136 + k * 32 + quad * 8];
        cm = mfma16(ap, WL2[2048 + (wq * 4 + k) * 64 + ln], cm);
        cs = mfma16(ap, WL2[2048 + ((wq + 4) * 4 + k) * 64 + ln], cs);
      }
      #pragma unroll
      for (int r = 0; r < 4; ++r) {
        float ps = softplus_f(cs[r]);
        float dm = zmK[r] - cm[r];
        float den = __expf(2.0f * ps) - 1.0f;
        kl_acc += 0.5f * (2.0f * __logf(ps + 0.01f) - 2.0f * __logf(zsK[r] + 0.01f)
                          + (zsK[r] * zsK[r] + dm * dm) / den);
      }
    }
    // streamed dec1 weights (consumed after gates; ~200cy of work covers L2)
    bf16x8 wD1s[4], w5s[2];
    #pragma unroll
    for (int k = 0; k < 4; ++k) wD1s[k] = WG2[cL6 + (wv * 4 + k) * 64 + ln];
    w5s[0] = WG2[cL5 + (wv * 2 + 0) * 64 + ln];
    w5s[1] = WG2[cL5 + (wv * 2 + 1) * 64 + ln];
    // prefetch next-step noise (vmcnt; unaffected by the lgkm fence below)
    if (t + 1 < TT) {
      #pragma unroll
      for (int nt = 0; nt < 4; ++nt)
        #pragma unroll
        for (int r = 0; r < 4; ++r)
          nz16[nt * 4 + r] =
              noise[((size_t)(t + 1) * BB + row0 + quad * 4 + r) * 64 + nt * 16 + col];
    }

    // ---- wave-local z convert: C-layout scratch -> A-fragments ----
    wave_lds_fence();
    bf16x8 az0 = *(const bf16x8*)&zscr[wv][col * 72 + 0 + quad * 8];
    bf16x8 az1 = *(const bf16x8*)&zscr[wv][col * 72 + 32 + quad * 8];

    // ---- gates-z + LSTM -> h ----
    #pragma unroll
    for (int i = 0; i < 4; ++i) {
      Cg[i] = mfma16(az0, rb9[i][0], Cg[i]);
      Cg[i] = mfma16(az1, rb9[i][1], Cg[i]);
    }
    #pragma unroll
    for (int r = 0; r < 4; ++r) {
      float gi = sigm(Cg[0][r]);
      float gf = sigm(Cg[1][r]);
      float gg = tanh_f(Cg[2][r]);
      float go = sigm(Cg[3][r]);
      float cn = gf * c_reg[r] + gi * gg;
      c_reg[r] = cn;
      A_h[cb ^ 1][(quad * 4 + r) * 136 + j_own] = (bf16_t)(go * tanh_f(cn));
    }
    // ---- dec1 (h_{t-1} from A_h[cb] + z) -> A_d1 ----
    {
      float bv = bsm[512 + nloc0];
      f32x4 c = {bv, bv, bv, bv};
      #pragma unroll
      for (int k = 0; k < 4; ++k) {
        bf16x8 ah = *(const bf16x8*)&A_h[cb][col * 136 + k * 32 + quad * 8];
        c = mfma16(ah, wD1s[k], c);
      }
      c = mfma16(az0, w5s[0], c);
      c = mfma16(az1, w5s[1], c);
      #pragma unroll
      for (int r = 0; r < 4; ++r)
        A_d1[(quad * 4 + r) * 136 + nloc0] = (bf16_t)fmaxf(c[r], 0.0f);
    }
    wg_barrier();  // B2
    cb ^= 1;
  }

  // ---- epilogue: final dec2 + recon for t = TT-1 (pre4 holds s[TT-1] on w4-7) ----
  if (wv >= 4) {
    int lzo = 0;
    asm volatile("" : "+s"(lzo));
    const bf16x8* WLe = (const bf16x8*)Wlds + lzo;
    float bv = bsm[640 + wq * 16 + col];
    f32x4 c = {bv, bv, bv, bv};
    #pragma unroll
    for (int k = 0; k < 4; ++k) {
      bf16x8 ad = *(const bf16x8*)&A_d1[col * 136 + k * 32 + quad * 8];
      c = mfma16(ad, WLe[6144 + (wq * 4 + k) * 64 + ln], c);
    }
    #pragma unroll
    for (int r = 0; r < 4; ++r) {
      float d = c[r] - pre4[r];
      rc_acc += 0.5f * d * d;
    }
  }

  float tot = (kl_acc + rc_acc) * (1.0f / 1024.0f);
  #pragma unroll
  for (int off = 32; off > 0; off >>= 1) tot += __shfl_down(tot, off);
  if (ln == 0) red[wv] = tot;
  __syncthreads();
  if (tid == 0) {
    float sum = 0.f;
    #pragma unroll
    for (int i = 0; i < 8; ++i) sum += red[i];
    atomicAdd(out, sum);
  }
}

extern "C" void kernel_launch(void* const* d_in, const int* in_sizes, int n_in,
                              void* d_out, int out_size, void* d_ws, size_t ws_size,
                              hipStream_t stream) {
  (void)in_sizes; (void)n_in; (void)out_size; (void)ws_size;
  const float* s   = (const float*)d_in[0];
  const float* nz  = (const float*)d_in[1];
  const float* Wps = (const float*)d_in[2];
  const float* bps = (const float*)d_in[3];
  const float* Wpz = (const float*)d_in[4];
  const float* bpz = (const float*)d_in[5];
  const float* Wp1 = (const float*)d_in[6];
  const float* bp1 = (const float*)d_in[7];
  const float* Wp2 = (const float*)d_in[8];
  const float* bp2 = (const float*)d_in[9];
  const float* We1 = (const float*)d_in[10];
  const float* be1 = (const float*)d_in[11];
  const float* We2 = (const float*)d_in[12];
  const float* be2 = (const float*)d_in[13];
  const float* Wih = (const float*)d_in[14];
  const float* bih = (const float*)d_in[15];
  const float* Whh = (const float*)d_in[16];
  const float* bhh = (const float*)d_in[17];
  const float* Wd1 = (const float*)d_in[18];
  const float* bd1 = (const float*)d_in[19];
  const float* Wd2 = (const float*)d_in[20];
  const float* bd2 = (const float*)d_in[21];

  bf16_t* packed = (bf16_t*)d_ws;
  float* fbias = (float*)((char*)d_ws + WS_FBIAS_OFF);
  float* fold  = (float*)((char*)d_ws + WS_FOLD_OFF);

  hipMemsetAsync(d_out, 0, sizeof(float), stream);
  vrnn_fold<<<(82688 + 255) / 256, 256, 0, stream>>>(We1, Wd1, Wih, Wps, Wpz, bps, bpz,
                                                     be1, bd1, bih, bhh, fold, fbias);
  vrnn_pack<<<(NCHUNK + 255) / 256, 256, 0, stream>>>(fold, We1, We2, Wp1, Wp2, Wd1, Wd2,
                                                      Whh, packed);
  vrnn_fuse2<<<64, 512, 0, stream>>>(s, nz, packed, fbias, bp1, bp2, be2, bd2,
                                     (float*)d_out);
}